// Round 16
// baseline (236.762 us; speedup 1.0000x reference)
//
#include <hip/hip_runtime.h>
#include <hip/hip_bf16.h>
#include <hip/hip_fp8.h>
#include <stdint.h>

#define NN 16384
#define DD 512
#define MARGINV 2.0f
#define EPSV 1e-6f

#define BJ 32
#define JGROUPS 8               // grid = 64 bi x 8 bj = 512 = exactly 2 blocks/CU, zero tail
#define JRANGE (NN / JGROUPS)   // 2048
#define NTILES (JRANGE / BJ)    // 64
#define ROWQ 512                // fp8 row bytes
#define TILEB (BJ * ROWQ)       // 16384 B per tile buffer
#define SQOFF (2 * TILEB)       // sqb LDS offset (8 KB region)

#define KEYMASK  0xFFFFC000     // keep sign+exp+9 mantissa bits; low 14 = j (j<16384)
#define KEYINITF __builtin_bit_cast(float, 0x7F000000)   // big positive finite float
#define BIASV 640.0f            // > max sq_i: keys strictly positive, self provably rank 0

typedef __attribute__((ext_vector_type(4))) float f32x4;
typedef __attribute__((ext_vector_type(4))) int   i32x4;
typedef __attribute__((ext_vector_type(8))) int   i32x8;

#define UNIT_SCALE 0x7F   // E8M0 biased exponent 127 -> x1.0

// sorted-2 insert: m0 <= m1 kept, insert u (2 ops)
__device__ inline void kins2f(float u, float& m0, float& m1) {
  m1 = __builtin_amdgcn_fmed3f(m0, m1, u);
  m0 = fminf(m0, u);
}

// ---------------- Kernel 1: row sq-norms (fp32, +BIASV) + fp8 e4m3 quantize ----------------
extern "C" __global__ __launch_bounds__(256)
void prep_kernel(const float* __restrict__ x, unsigned char* __restrict__ xq,
                 float* __restrict__ sqb) {
  int row  = blockIdx.x * 4 + (threadIdx.x >> 6);
  int lane = threadIdx.x & 63;
  const float* xr = x + (size_t)row * DD + lane * 8;
  f32x4 a = *(const f32x4*)xr;
  f32x4 b = *(const f32x4*)(xr + 4);
  float s = a[0]*a[0]+a[1]*a[1]+a[2]*a[2]+a[3]*a[3]
          + b[0]*b[0]+b[1]*b[1]+b[2]*b[2]+b[3]*b[3];
  #pragma unroll
  for (int off = 1; off < 64; off <<= 1) s += __shfl_xor(s, off, 64);
  unsigned int w0 = (unsigned int)__builtin_amdgcn_cvt_pk_fp8_f32(a[0], a[1], 0, false);
  w0 = (unsigned int)__builtin_amdgcn_cvt_pk_fp8_f32(a[2], a[3], (int)w0, true);
  unsigned int w1 = (unsigned int)__builtin_amdgcn_cvt_pk_fp8_f32(b[0], b[1], 0, false);
  w1 = (unsigned int)__builtin_amdgcn_cvt_pk_fp8_f32(b[2], b[3], (int)w1, true);
  unsigned long long pk8 = ((unsigned long long)w1 << 32) | (unsigned long long)w0;
  *(unsigned long long*)(xq + (size_t)row * ROWQ + lane * 8) = pk8;
  if (lane == 0) sqb[row] = s + BIASV;
}

// ---------------- Kernel 2: fused MX-fp8 GEMM (X·X^T) + per-row packed top-2 -------------
// FINAL VERIFIED BEST (r8: 147.7 us, r14: 150.2 us; total 227.3-228.0 us, 124 VGPR,
// no spill, MfmaUtil ~40%). 256 thr / 4 waves x 64 i-rows, afr 4x4 resident (128 AGPR
// of the unified 256/wave), acc[4] inside jh loop, fully inline hot loop,
// top-2-excluding-self with branch-free jrel compare. Complete lever disposition:
//   - top-2 + branch-free epilogue: WON (kept).
//   - register restructures (r2 ping-pong, r3 reg-cap, r4/r5 array-param lambdas,
//     r6 LICM hoist): all spill. VGPR-side liveness <= ~124; afr must stay intact.
//   - occupancy changes (r3 8-wave, r5 128-thr): remat / no gain.
//   - BJ=64 (r9): -5%. setprio sym/asym (m190/r10): null. sqb LDS vs global: null.
//   - kernel fusion (r11-r13): cooperative launch not graph-capturable; manual grid
//     barrier -> deterministic stale-read (agent AND system fences). Abandoned.
//   - T4 counted vmcnt, quad-buffer (r15): null -- staged tiles are L2-resident
//     (FETCH 35 MB vs 8 MB working set), drain costs ~200-300 cyc, not the stall.
// Remaining headroom (40 -> 60% MfmaUtil) requires the 8-phase 256^2 schedule or
// triangle symmetry -- both incompatible with the 4-reg headroom + pinned A-file.
extern "C" __global__ __launch_bounds__(256, 2)
void knn_kernel(const unsigned char* __restrict__ xq, const float* __restrict__ sqb,
                int* __restrict__ pk) {
  __shared__ __align__(16) char lds[2 * TILEB + 8192];  // 40,960 B
  const int tid  = threadIdx.x;
  const int wave = tid >> 6;
  const int lane = tid & 63;
  const int quad = lane >> 4;
  const int r16  = lane & 15;
  const int bi   = blockIdx.x >> 3;             // 0..63
  const int bj   = blockIdx.x & 7;              // 0..7
  const int ibase = bi * 256 + wave * 64;       // 64 i-rows per wave
  const int jbase = bj * JRANGE;

  // stage sqb[jbase .. jbase+2048) into LDS (8 KB): 2 passes x (4 waves x 64 lanes x 16 B)
  #pragma unroll
  for (int p = 0; p < 2; ++p) {
    const float* gs = sqb + jbase + p * 1024 + wave * 256 + lane * 4;
    char* ld = lds + SQOFF + p * 4096 + wave * 1024;    // wave-uniform base
    __builtin_amdgcn_global_load_lds((const __attribute__((address_space(1))) void*)gs,
                                     (__attribute__((address_space(3))) void*)ld,
                                     16, 0, 0);
  }

  // A fragments: 4 sets x 4 k-chunks x 32 B (v8i32). A[m=r16][k=chunk*128+quad*32+t]
  i32x8 afr[4][4];
  #pragma unroll
  for (int s = 0; s < 4; ++s) {
    const unsigned char* ar = xq + (size_t)(ibase + s * 16 + r16) * ROWQ + quad * 32;
    #pragma unroll
    for (int c = 0; c < 4; ++c)
      afr[s][c] = *(const i32x8*)(ar + c * 128);
  }

  // packed top-2 (non-self) per (set s, reg r): q = s*4 + r
  float m0[16], m1[16];
  #pragma unroll
  for (int q = 0; q < 16; ++q) { m0[q] = m1[q] = KEYINITF; }

  auto stage = [&](int jt, int buf) {
    const int jrow0 = jbase + jt * BJ;
    #pragma unroll
    for (int p = 0; p < 4; ++p) {
      const int rr = wave * 8 + p * 2;                     // wave-uniform local row pair
      const int lr = rr + (lane >> 5);                     // per-lane local row
      const int u  = (lane & 31) ^ (lr & 7);               // FULL 3-bit swizzle
      const unsigned char* gsrc = xq + (size_t)(jrow0 + lr) * ROWQ + u * 16;
      char* ldst = lds + buf * TILEB + rr * ROWQ;          // wave-uniform base
      __builtin_amdgcn_global_load_lds((const __attribute__((address_space(1))) void*)gsrc,
                                       (__attribute__((address_space(3))) void*)ldst,
                                       16, 0, 0);
    }
  };

  const int sw = r16 & 7;
  stage(0, 0);
  for (int jt = 0; jt < NTILES; ++jt) {
    __syncthreads();
    if (jt + 1 < NTILES) stage(jt + 1, (jt + 1) & 1);
    #pragma unroll
    for (int jh = 0; jh < 2; ++jh) {
      const char* brow = lds + (jt & 1) * TILEB + (jh * 16 + r16) * ROWQ;
      // sqj from LDS (broadcast across quads: conflict-free), lgkm counter not vmcnt
      const float sqj = *(const float*)(lds + SQOFF + ((jt * BJ + jh * 16 + r16) << 2));
      f32x4 acc[4] = {{0.f,0.f,0.f,0.f},{0.f,0.f,0.f,0.f},
                      {0.f,0.f,0.f,0.f},{0.f,0.f,0.f,0.f}};
      #pragma unroll
      for (int c = 0; c < 4; ++c) {
        const int g0 = c * 8 + quad * 2;
        i32x4 lo = *(const i32x4*)(brow + ((g0       ^ sw) * 16));
        i32x4 hi = *(const i32x4*)(brow + (((g0 + 1) ^ sw) * 16));
        i32x8 bf = i32x8{lo[0],lo[1],lo[2],lo[3],hi[0],hi[1],hi[2],hi[3]};
        #pragma unroll
        for (int s = 0; s < 4; ++s)
          acc[s] = __builtin_amdgcn_mfma_scale_f32_16x16x128_f8f6f4(
                     afr[s][c], bf, acc[s], 0, 0, 0, UNIT_SCALE, 0, UNIT_SCALE);
      }
      const int j = jbase + jt * BJ + jh * 16 + r16;
      // self iff j == ibase + s*16 + quad*4 + r  <=>  jrel == s*16 + r (inline consts);
      // automatically false off-diagonal -- no branch needed.
      const int jrel = j - ibase - quad * 4;
      #pragma unroll
      for (int s = 0; s < 4; ++s)
      #pragma unroll
      for (int r = 0; r < 4; ++r) {
        float v = fmaf(-2.0f, acc[s][r], sqj);             // > 0 by BIASV construction
        int   b = (__builtin_bit_cast(int, v) & KEYMASK) | j;   // v_and_or_b32
        float u = __builtin_bit_cast(float, b);
        u = (jrel == (s * 16 + r)) ? KEYINITF : u;         // exclude self (cndmask)
        kins2f(u, m0[s*4+r], m1[s*4+r]);
      }
    }
  }

  // ------- in-register butterfly merge across r16 (masks 1,2,4,8 stay in-quad) -------
  #pragma unroll
  for (int m = 1; m <= 8; m <<= 1) {
    #pragma unroll
    for (int q = 0; q < 16; ++q) {
      float o0 = __shfl_xor(m0[q], m, 64);
      float o1 = __shfl_xor(m1[q], m, 64);
      kins2f(o0, m0[q], m1[q]);
      kins2f(o1, m0[q], m1[q]);
    }
  }

  // lane with r16 == q writes row q's merged packed top-2 (16 writers x 4 quads)
  #pragma unroll
  for (int q = 0; q < 16; ++q) {
    if (r16 == q) {
      int s  = q >> 2, r = q & 3;
      int gi = ibase + s * 16 + quad * 4 + r;
      int ob = (gi * JGROUPS + bj) * 2;
      pk[ob + 0] = __builtin_bit_cast(int, m0[q]);
      pk[ob + 1] = __builtin_bit_cast(int, m1[q]);
    }
  }
}

// ---------------- Kernel 3: merge partials, fp32 norms, hinge -> per-block partial ----
// r3-r15 verified: parallel 16-lane pk merge + butterfly; 2048 blocks; no atomics.
extern "C" __global__ __launch_bounds__(256)
void finalize_kernel(const float* __restrict__ x, const float* __restrict__ pos,
                     const int* __restrict__ pk, float* __restrict__ partial) {
  __shared__ float wsum[4];
  int wave = threadIdx.x >> 6;
  int lane = threadIdx.x & 63;
  float acc = 0.f;
  #pragma unroll
  for (int rep = 0; rep < 2; ++rep) {
    int i = rep * 8192 + blockIdx.x * 4 + wave;
    // parallel top-2 merge of 16 packed keys: lanes 0..15 hold one key each
    float m0 = (lane < 16) ? __builtin_bit_cast(float, pk[i * 16 + lane]) : KEYINITF;
    float m1 = KEYINITF;
    #pragma unroll
    for (int m = 1; m <= 8; m <<= 1) {
      float o0 = __shfl_xor(m0, m, 64);
      float o1 = __shfl_xor(m1, m, 64);
      float t0 = fminf(m0, o0);
      m1 = fminf(fmaxf(m0, o0), fminf(m1, o1));   // 2nd smallest of sorted-pair union
      m0 = t0;
    }
    int neg = __shfl(__builtin_bit_cast(int, m1), 0, 64) & 0x3FFF;  // global rank-2
    const float* xr = x   + (size_t)i * DD + lane * 8;
    const float* pr = pos + (size_t)i * DD + lane * 8;
    const float* nr = x   + (size_t)neg * DD + lane * 8;
    f32x4 xa = *(const f32x4*)xr, xb4 = *(const f32x4*)(xr + 4);
    f32x4 pa = *(const f32x4*)pr, pb  = *(const f32x4*)(pr + 4);
    f32x4 na = *(const f32x4*)nr, nb  = *(const f32x4*)(nr + 4);
    float sap = 0.f, san = 0.f;
    #pragma unroll
    for (int k = 0; k < 4; ++k) {
      float d0 = xa[k]  - pa[k] + EPSV; sap = fmaf(d0, d0, sap);
      float d1 = xa[k]  - na[k] + EPSV; san = fmaf(d1, d1, san);
      float d2 = xb4[k] - pb[k] + EPSV; sap = fmaf(d2, d2, sap);
      float d3 = xb4[k] - nb[k] + EPSV; san = fmaf(d3, d3, san);
    }
    #pragma unroll
    for (int off = 1; off < 64; off <<= 1) {
      sap += __shfl_xor(sap, off, 64);
      san += __shfl_xor(san, off, 64);
    }
    if (lane == 0) {
      float l = sqrtf(sap) - sqrtf(san) + MARGINV;
      acc += (l > 0.f ? l : 0.f);
    }
  }
  if (lane == 0) wsum[wave] = acc;
  __syncthreads();
  if (threadIdx.x == 0) partial[blockIdx.x] = wsum[0] + wsum[1] + wsum[2] + wsum[3];
}

// ---------------- Kernel 4: reduce 2048 partials -> loss ----------------
extern "C" __global__ __launch_bounds__(256)
void reduce_kernel(const float* __restrict__ partial, float* __restrict__ out) {
  __shared__ float wsum[4];
  int tid = threadIdx.x;
  float s = 0.f;
  #pragma unroll
  for (int k = 0; k < 8; ++k) s += partial[tid + k * 256];
  #pragma unroll
  for (int off = 1; off < 64; off <<= 1) s += __shfl_xor(s, off, 64);
  if ((tid & 63) == 0) wsum[tid >> 6] = s;
  __syncthreads();
  if (tid == 0) out[0] = (wsum[0] + wsum[1] + wsum[2] + wsum[3]) * (1.0f / NN);
}

// ---------------- host ----------------
extern "C" void kernel_launch(void* const* d_in, const int* in_sizes, int n_in,
                              void* d_out, int out_size, void* d_ws, size_t ws_size,
                              hipStream_t stream) {
  const float* x   = (const float*)d_in[0];
  const float* pos = (const float*)d_in[1];
  char* ws = (char*)d_ws;
  unsigned char* xq   = (unsigned char*)ws;                                   // 8 MB
  float* sqb  = (float*)(ws + (size_t)NN * ROWQ);                             // 64 KB
  int*   pk   = (int*)  (ws + (size_t)NN * ROWQ + (size_t)NN * 4);            // 1 MB
  float* part = (float*)(ws + (size_t)NN * ROWQ + (size_t)NN * 4
                            + (size_t)NN * JGROUPS * 2 * 4);                  // 8 KB

  prep_kernel<<<NN / 4, 256, 0, stream>>>(x, xq, sqb);
  knn_kernel<<<(NN / 256) * JGROUPS, 256, 0, stream>>>(xq, sqb, pk);
  finalize_kernel<<<2048, 256, 0, stream>>>(x, pos, pk, part);
  reduce_kernel<<<1, 256, 0, stream>>>(part, (float*)d_out);
}

// Round 17
// 213.985 us; speedup vs baseline: 1.1064x; 1.1064x over previous
//
#include <hip/hip_runtime.h>
#include <hip/hip_bf16.h>
#include <hip/hip_fp8.h>
#include <stdint.h>

#define NN 16384
#define DD 512
#define MARGINV 2.0f
#define EPSV 1e-6f

#define BJ 32
#define JGROUPS 8               // grid = 64 bi x 8 bj = 512 = exactly 2 blocks/CU, zero tail
#define JRANGE (NN / JGROUPS)   // 2048
#define NTILES (JRANGE / BJ)    // 64
#define ROWQ 512                // row bytes: 16 cells x (24 B fp6 data + 8 B pad)
#define TILEB (BJ * ROWQ)       // 16384 B per tile buffer
#define SQOFF (2 * TILEB)       // sqb LDS offset (8 KB region)

#define KEYMASK  0xFFFFC000     // keep sign+exp+9 mantissa bits; low 14 = j (j<16384)
#define KEYINITF __builtin_bit_cast(float, 0x7F000000)   // big positive finite float
#define BIASV 640.0f            // > max sq_i: keys strictly positive, self provably rank 0

typedef __attribute__((ext_vector_type(4))) float f32x4;
typedef __attribute__((ext_vector_type(4))) int   i32x4;
typedef __attribute__((ext_vector_type(2))) int   i32x2;
typedef __attribute__((ext_vector_type(8))) int   i32x8;

#define UNIT_SCALE 0x7F   // E8M0 biased exponent 127 -> x1.0
#define FMT_FP6 2         // f8f6f4 FMT: 0=fp8 e4m3, 2=fp6 e2m3 (runs at fp4 rate, 1.55x fp8)

// sorted-2 insert: m0 <= m1 kept, insert u (2 ops)
__device__ inline void kins2f(float u, float& m0, float& m1) {
  m1 = __builtin_amdgcn_fmed3f(m0, m1, u);
  m0 = fminf(m0, u);
}

// e2m3 encode, exact nearest (RNE at region midpoints 1.9375 / 3.875 handled by
// strict-< branch bounds). code c = e*8+m; for a<2 the set {k*0.125} is linear in c.
__device__ inline unsigned int enc_e2m3(float v) {
  float a = fabsf(v);
  unsigned int s = (__builtin_bit_cast(unsigned int, v) >> 31) << 5;
  float c;
  if (a < 1.9375f)     c = __builtin_rintf(a * 8.0f);                       // 0..15
  else if (a < 3.875f) c = 16.0f + __builtin_rintf((a - 2.0f) * 4.0f);      // 16..23
  else                 c = 24.0f + __builtin_rintf(fminf((a - 4.0f) * 2.0f, 7.0f));
  return s | (unsigned int)c;
}

// ---------------- Kernel 1: row sq-norms (fp32, +BIASV) + fp6 e2m3 quantize ----------------
// Cell layout: row = 16 cells of 32 B at (k/128)*128 + ((k%128)/32)*32; cell holds 32
// values x 6 bit packed k-ascending LSB-first in bytes 0-23; bytes 24-31 pad (never
// read into MFMA operands). Lane covers k in [lane*8, lane*8+8) -> 48 bits at byte
// (lane&3)*6 of cell (lane>>4, (lane>>2)&3). 3x u16 stores (2-aligned at 0/2/4 of 6).
extern "C" __global__ __launch_bounds__(256)
void prep_kernel(const float* __restrict__ x, unsigned char* __restrict__ xq,
                 float* __restrict__ sqb) {
  int row  = blockIdx.x * 4 + (threadIdx.x >> 6);
  int lane = threadIdx.x & 63;
  const float* xr = x + (size_t)row * DD + lane * 8;
  f32x4 va = *(const f32x4*)xr;
  f32x4 vb = *(const f32x4*)(xr + 4);
  float s = va[0]*va[0]+va[1]*va[1]+va[2]*va[2]+va[3]*va[3]
          + vb[0]*vb[0]+vb[1]*vb[1]+vb[2]*vb[2]+vb[3]*vb[3];
  #pragma unroll
  for (int off = 1; off < 64; off <<= 1) s += __shfl_xor(s, off, 64);
  unsigned long long pk6 = 0;
  #pragma unroll
  for (int t = 0; t < 4; ++t) {
    pk6 |= ((unsigned long long)enc_e2m3(va[t])) << (6 * t);
    pk6 |= ((unsigned long long)enc_e2m3(vb[t])) << (6 * (t + 4));
  }
  unsigned char* dst = xq + (size_t)row * ROWQ
                     + (lane >> 4) * 128 + ((lane >> 2) & 3) * 32 + (lane & 3) * 6;
  *(unsigned short*)(dst + 0) = (unsigned short)(pk6);
  *(unsigned short*)(dst + 2) = (unsigned short)(pk6 >> 16);
  *(unsigned short*)(dst + 4) = (unsigned short)(pk6 >> 32);
  if (lane == 0) sqb[row] = s + BIASV;
}

// ---------------- Kernel 2: fused MX-fp6 GEMM (X·X^T) + per-row packed top-2 -------------
// r8/r14 schedule VERBATIM (147.7-150.2 us verified); single change: fp8 -> fp6 e2m3
// operands (cbsz=blgp=2). Same MFMA count, same K=128 shape, 1.55x rate (fp6 runs at
// the fp4 rate on CDNA4). Rows stay 512 B (padded cells) -> staging/swizzle/addressing
// byte-identical; operand reads become b128+b64 (24 B of each 32-B cell; pad never
// loaded into operands). afr shrinks 128 -> 96 regs (+32 headroom vs r8).
// Accuracy: e2m3 key-noise std ~2.5 vs rank-3 order-stat gap ~12 -> ~1e-3 swap prob,
// ~20/16384 rows change pick, finalize recomputes d_an in exact fp32 -> |dloss|~5e-4.
// Guards: VGPR <= 124, WRITE_SIZE 4096 KB, LDS 40960, FETCH ~34.9 MB.
extern "C" __global__ __launch_bounds__(256, 2)
void knn_kernel(const unsigned char* __restrict__ xq, const float* __restrict__ sqb,
                int* __restrict__ pk) {
  __shared__ __align__(16) char lds[2 * TILEB + 8192];  // 40,960 B
  const int tid  = threadIdx.x;
  const int wave = tid >> 6;
  const int lane = tid & 63;
  const int quad = lane >> 4;
  const int r16  = lane & 15;
  const int bi   = blockIdx.x >> 3;             // 0..63
  const int bj   = blockIdx.x & 7;              // 0..7
  const int ibase = bi * 256 + wave * 64;       // 64 i-rows per wave
  const int jbase = bj * JRANGE;

  // stage sqb[jbase .. jbase+2048) into LDS (8 KB): 2 passes x (4 waves x 64 lanes x 16 B)
  #pragma unroll
  for (int p = 0; p < 2; ++p) {
    const float* gs = sqb + jbase + p * 1024 + wave * 256 + lane * 4;
    char* ld = lds + SQOFF + p * 4096 + wave * 1024;    // wave-uniform base
    __builtin_amdgcn_global_load_lds((const __attribute__((address_space(1))) void*)gs,
                                     (__attribute__((address_space(3))) void*)ld,
                                     16, 0, 0);
  }

  // A fragments: 4 sets x 4 k-chunks x 24 B (i32x4 + i32x2) = 96 regs
  i32x4 afr4[4][4];
  i32x2 afr2[4][4];
  #pragma unroll
  for (int s = 0; s < 4; ++s) {
    const unsigned char* ar = xq + (size_t)(ibase + s * 16 + r16) * ROWQ + quad * 32;
    #pragma unroll
    for (int c = 0; c < 4; ++c) {
      afr4[s][c] = *(const i32x4*)(ar + c * 128);
      afr2[s][c] = *(const i32x2*)(ar + c * 128 + 16);
    }
  }

  // packed top-2 (non-self) per (set s, reg r): q = s*4 + r
  float m0[16], m1[16];
  #pragma unroll
  for (int q = 0; q < 16; ++q) { m0[q] = m1[q] = KEYINITF; }

  auto stage = [&](int jt, int buf) {
    const int jrow0 = jbase + jt * BJ;
    #pragma unroll
    for (int p = 0; p < 4; ++p) {
      const int rr = wave * 8 + p * 2;                     // wave-uniform local row pair
      const int lr = rr + (lane >> 5);                     // per-lane local row
      const int u  = (lane & 31) ^ (lr & 7);               // FULL 3-bit swizzle
      const unsigned char* gsrc = xq + (size_t)(jrow0 + lr) * ROWQ + u * 16;
      char* ldst = lds + buf * TILEB + rr * ROWQ;          // wave-uniform base
      __builtin_amdgcn_global_load_lds((const __attribute__((address_space(1))) void*)gsrc,
                                       (__attribute__((address_space(3))) void*)ldst,
                                       16, 0, 0);
    }
  };

  const int sw = r16 & 7;
  stage(0, 0);
  for (int jt = 0; jt < NTILES; ++jt) {
    __syncthreads();
    if (jt + 1 < NTILES) stage(jt + 1, (jt + 1) & 1);
    #pragma unroll
    for (int jh = 0; jh < 2; ++jh) {
      const char* brow = lds + (jt & 1) * TILEB + (jh * 16 + r16) * ROWQ;
      // sqj from LDS (broadcast across quads: conflict-free), lgkm counter not vmcnt
      const float sqj = *(const float*)(lds + SQOFF + ((jt * BJ + jh * 16 + r16) << 2));
      f32x4 acc[4] = {{0.f,0.f,0.f,0.f},{0.f,0.f,0.f,0.f},
                      {0.f,0.f,0.f,0.f},{0.f,0.f,0.f,0.f}};
      #pragma unroll
      for (int c = 0; c < 4; ++c) {
        const int g0 = c * 8 + quad * 2;
        i32x4 lo = *(const i32x4*)(brow + ((g0       ^ sw) * 16));
        i32x2 hi = *(const i32x2*)(brow + (((g0 + 1) ^ sw) * 16));
        i32x8 bf = i32x8{lo[0],lo[1],lo[2],lo[3],hi[0],hi[1],0,0};
        #pragma unroll
        for (int s = 0; s < 4; ++s) {
          i32x8 af = i32x8{afr4[s][c][0],afr4[s][c][1],afr4[s][c][2],afr4[s][c][3],
                           afr2[s][c][0],afr2[s][c][1],0,0};
          acc[s] = __builtin_amdgcn_mfma_scale_f32_16x16x128_f8f6f4(
                     af, bf, acc[s], FMT_FP6, FMT_FP6, 0, UNIT_SCALE, 0, UNIT_SCALE);
        }
      }
      const int j = jbase + jt * BJ + jh * 16 + r16;
      // self iff j == ibase + s*16 + quad*4 + r  <=>  jrel == s*16 + r (inline consts);
      // automatically false off-diagonal -- no branch needed.
      const int jrel = j - ibase - quad * 4;
      #pragma unroll
      for (int s = 0; s < 4; ++s)
      #pragma unroll
      for (int r = 0; r < 4; ++r) {
        float v = fmaf(-2.0f, acc[s][r], sqj);             // > 0 by BIASV construction
        int   b = (__builtin_bit_cast(int, v) & KEYMASK) | j;   // v_and_or_b32
        float u = __builtin_bit_cast(float, b);
        u = (jrel == (s * 16 + r)) ? KEYINITF : u;         // exclude self (cndmask)
        kins2f(u, m0[s*4+r], m1[s*4+r]);
      }
    }
  }

  // ------- in-register butterfly merge across r16 (masks 1,2,4,8 stay in-quad) -------
  #pragma unroll
  for (int m = 1; m <= 8; m <<= 1) {
    #pragma unroll
    for (int q = 0; q < 16; ++q) {
      float o0 = __shfl_xor(m0[q], m, 64);
      float o1 = __shfl_xor(m1[q], m, 64);
      kins2f(o0, m0[q], m1[q]);
      kins2f(o1, m0[q], m1[q]);
    }
  }

  // lane with r16 == q writes row q's merged packed top-2 (16 writers x 4 quads)
  #pragma unroll
  for (int q = 0; q < 16; ++q) {
    if (r16 == q) {
      int s  = q >> 2, r = q & 3;
      int gi = ibase + s * 16 + quad * 4 + r;
      int ob = (gi * JGROUPS + bj) * 2;
      pk[ob + 0] = __builtin_bit_cast(int, m0[q]);
      pk[ob + 1] = __builtin_bit_cast(int, m1[q]);
    }
  }
}

// ---------------- Kernel 3: merge partials, fp32 norms, hinge -> per-block partial ----
// r3-r16 verified: parallel 16-lane pk merge + butterfly; 2048 blocks; no atomics.
// Norms computed in exact fp32 from x -> quantization only affects neighbor CHOICE.
extern "C" __global__ __launch_bounds__(256)
void finalize_kernel(const float* __restrict__ x, const float* __restrict__ pos,
                     const int* __restrict__ pk, float* __restrict__ partial) {
  __shared__ float wsum[4];
  int wave = threadIdx.x >> 6;
  int lane = threadIdx.x & 63;
  float acc = 0.f;
  #pragma unroll
  for (int rep = 0; rep < 2; ++rep) {
    int i = rep * 8192 + blockIdx.x * 4 + wave;
    // parallel top-2 merge of 16 packed keys: lanes 0..15 hold one key each
    float m0 = (lane < 16) ? __builtin_bit_cast(float, pk[i * 16 + lane]) : KEYINITF;
    float m1 = KEYINITF;
    #pragma unroll
    for (int m = 1; m <= 8; m <<= 1) {
      float o0 = __shfl_xor(m0, m, 64);
      float o1 = __shfl_xor(m1, m, 64);
      float t0 = fminf(m0, o0);
      m1 = fminf(fmaxf(m0, o0), fminf(m1, o1));   // 2nd smallest of sorted-pair union
      m0 = t0;
    }
    int neg = __shfl(__builtin_bit_cast(int, m1), 0, 64) & 0x3FFF;  // global rank-2
    const float* xr = x   + (size_t)i * DD + lane * 8;
    const float* pr = pos + (size_t)i * DD + lane * 8;
    const float* nr = x   + (size_t)neg * DD + lane * 8;
    f32x4 xa = *(const f32x4*)xr, xb4 = *(const f32x4*)(xr + 4);
    f32x4 pa = *(const f32x4*)pr, pb  = *(const f32x4*)(pr + 4);
    f32x4 na = *(const f32x4*)nr, nb  = *(const f32x4*)(nr + 4);
    float sap = 0.f, san = 0.f;
    #pragma unroll
    for (int k = 0; k < 4; ++k) {
      float d0 = xa[k]  - pa[k] + EPSV; sap = fmaf(d0, d0, sap);
      float d1 = xa[k]  - na[k] + EPSV; san = fmaf(d1, d1, san);
      float d2 = xb4[k] - pb[k] + EPSV; sap = fmaf(d2, d2, sap);
      float d3 = xb4[k] - nb[k] + EPSV; san = fmaf(d3, d3, san);
    }
    #pragma unroll
    for (int off = 1; off < 64; off <<= 1) {
      sap += __shfl_xor(sap, off, 64);
      san += __shfl_xor(san, off, 64);
    }
    if (lane == 0) {
      float l = sqrtf(sap) - sqrtf(san) + MARGINV;
      acc += (l > 0.f ? l : 0.f);
    }
  }
  if (lane == 0) wsum[wave] = acc;
  __syncthreads();
  if (threadIdx.x == 0) partial[blockIdx.x] = wsum[0] + wsum[1] + wsum[2] + wsum[3];
}

// ---------------- Kernel 4: reduce 2048 partials -> loss ----------------
extern "C" __global__ __launch_bounds__(256)
void reduce_kernel(const float* __restrict__ partial, float* __restrict__ out) {
  __shared__ float wsum[4];
  int tid = threadIdx.x;
  float s = 0.f;
  #pragma unroll
  for (int k = 0; k < 8; ++k) s += partial[tid + k * 256];
  #pragma unroll
  for (int off = 1; off < 64; off <<= 1) s += __shfl_xor(s, off, 64);
  if ((tid & 63) == 0) wsum[tid >> 6] = s;
  __syncthreads();
  if (tid == 0) out[0] = (wsum[0] + wsum[1] + wsum[2] + wsum[3]) * (1.0f / NN);
}

// ---------------- host ----------------
extern "C" void kernel_launch(void* const* d_in, const int* in_sizes, int n_in,
                              void* d_out, int out_size, void* d_ws, size_t ws_size,
                              hipStream_t stream) {
  const float* x   = (const float*)d_in[0];
  const float* pos = (const float*)d_in[1];
  char* ws = (char*)d_ws;
  unsigned char* xq   = (unsigned char*)ws;                                   // 8 MB
  float* sqb  = (float*)(ws + (size_t)NN * ROWQ);                             // 64 KB
  int*   pk   = (int*)  (ws + (size_t)NN * ROWQ + (size_t)NN * 4);            // 1 MB
  float* part = (float*)(ws + (size_t)NN * ROWQ + (size_t)NN * 4
                            + (size_t)NN * JGROUPS * 2 * 4);                  // 8 KB

  prep_kernel<<<NN / 4, 256, 0, stream>>>(x, xq, sqb);
  knn_kernel<<<(NN / 256) * JGROUPS, 256, 0, stream>>>(xq, sqb, pk);
  finalize_kernel<<<2048, 256, 0, stream>>>(x, pos, pk, part);
  reduce_kernel<<<1, 256, 0, stream>>>(part, (float*)d_out);
}